// Round 6
// baseline (69.234 us; speedup 1.0000x reference)
//
#include <hip/hip_runtime.h>
#include <math.h>

namespace {

constexpr int kB = 16384;  // batch rows
constexpr int kD = 512;    // feature dim
constexpr int kC = 1000;   // classes

typedef __attribute__((ext_vector_type(8))) short s8v;   // 8 bf16 = 4 VGPRs
typedef __attribute__((ext_vector_type(4))) float f4v;   // MFMA acc

union V8 { unsigned short u[8]; s8v v; };

__device__ inline unsigned short f2bf(float f) {  // round-to-nearest-even
  unsigned int u = __float_as_uint(f);
  return (unsigned short)((u + 0x7FFFu + ((u >> 16) & 1u)) >> 16);
}

// --- k_prep: fused column-norm + pack normalized bf16 B-fragments --------
// 64 blocks x 256 threads; block = one 16-col class tile (tile 63 -> zeros).
// pb[frag=ct*16+ks][lane][j] = bf16(center[ks*32+(lane>>4)*8+j][ct*16+(lane&15)]*inv)
__global__ __launch_bounds__(256)
void k_prep(const float* __restrict__ center, unsigned short* __restrict__ pb,
            float* __restrict__ out) {
  if (blockIdx.x == 0 && threadIdx.x == 0) out[0] = 0.f;  // zero accumulator
  __shared__ float Ct[kD][16];  // 32 KB
  __shared__ float P[16][16];
  __shared__ float inv[16];
  const int t = threadIdx.x, ct = blockIdx.x;
  const int col = t & 15, dg = t >> 4;
  const int cc = ct * 16 + col;
  float s = 0.f;
#pragma unroll 8
  for (int j = 0; j < 32; ++j) {
    int d = dg * 32 + j;
    float v = (cc < kC) ? center[(size_t)d * kC + cc] : 0.f;
    Ct[d][col] = v;
    s = fmaf(v, v, s);
  }
  P[dg][col] = s;
  __syncthreads();
  if (t < 16) {
    float tot = 0.f;
#pragma unroll
    for (int j = 0; j < 16; ++j) tot += P[j][t];
    inv[t] = rsqrtf(fmaxf(tot, 1e-24f));  // == 1/max(||c||,1e-12)
  }
  __syncthreads();
#pragma unroll
  for (int pi = 0; pi < 4; ++pi) {
    int p = t * 4 + pi;            // 1024 (ks,lane) fragment-slots
    int ks = p >> 6, lane = p & 63;
    int cl = lane & 15, d0 = ks * 32 + ((lane >> 4) << 3);
    float iv = inv[cl];
    V8 o;
#pragma unroll
    for (int j = 0; j < 8; ++j) o.u[j] = f2bf(Ct[d0 + j][cl] * iv);
    *(s8v*)(pb + ((size_t)(ct * 16 + ks) * 64 + lane) * 8) = o.v;
  }
}

// --- k_main: pinned-A registers + depth-3 B-ring pipeline + lean softmax --
// 256 blocks x 512 threads (8 waves). Block = 64 rows. Wave (rg,tg): rows
// rg*32.., class tiles tg*16..+16. A in 128 pinned VGPRs; B streams from L2
// through a 4-slot register ring with 12 loads permanently in flight.
__global__ __launch_bounds__(512, 2)
void k_main(const float* __restrict__ features,
            const int* __restrict__ labels,
            const unsigned short* __restrict__ pb,
            float* __restrict__ out) {
  __shared__ __align__(16) unsigned short Ab[64 * kD];  // 64 KB, swizzled
  char* lds = (char*)Ab;
  float* Sf = (float*)Ab;  // overlay for final merge (A dead by then)
  const int t = threadIdx.x;
  const int w = t >> 6, lane = t & 63;
  const int rg = w >> 2, tg = w & 3;
  const int b0r = blockIdx.x * 64;

  // stage 64x512 f32 -> bf16 -> LDS with 16B XOR swizzle
#pragma unroll
  for (int i = 0; i < 8; ++i) {
    int c = i * 512 + t;  // chunk of 8 bf16
    int row = c >> 6, kc = c & 63;
    const float* src = features + (size_t)(b0r + row) * kD + kc * 8;
    float4 f0 = *(const float4*)src;
    float4 f1 = *(const float4*)(src + 4);
    V8 h;
    h.u[0] = f2bf(f0.x); h.u[1] = f2bf(f0.y); h.u[2] = f2bf(f0.z); h.u[3] = f2bf(f0.w);
    h.u[4] = f2bf(f1.x); h.u[5] = f2bf(f1.y); h.u[6] = f2bf(f1.z); h.u[7] = f2bf(f1.w);
    int byteoff = row * 1024 + ((kc * 16) ^ ((row & 7) << 4));
    *(s8v*)(lds + byteoff) = h.v;
  }
  __syncthreads();

  // load this wave's 32 rows x K=512 of A into 128 VGPRs, then PIN them
  const int q16 = (lane >> 4) << 4;
  s8v a[2][16];
#pragma unroll
  for (int rt = 0; rt < 2; ++rt) {
    const int row = rg * 32 + rt * 16 + (lane & 15);
    const int rb = row * 1024, swz = (row & 7) << 4;
#pragma unroll
    for (int ks = 0; ks < 16; ++ks)
      a[rt][ks] = *(const s8v*)(lds + rb + ((ks * 64 + q16) ^ swz));
  }
#pragma unroll
  for (int rt = 0; rt < 2; ++rt)
#pragma unroll
    for (int ks = 0; ks < 16; ++ks)
      asm volatile("" : "+v"(a[rt][ks]));

  // per-lane state (no running max: |logit| <= ||f|| ~ 25, exp() is safe)
  float l[8], zl[8];
  int lab[8];
#pragma unroll
  for (int s = 0; s < 8; ++s) {
    l[s] = 0.f; zl[s] = 0.f;
    lab[s] = labels[b0r + rg * 32 + (s >> 2) * 16 + ((lane >> 4) << 2) + (s & 3)];
  }

  // quarter q (0..63): tile tg*16 + (q>>2), k-frags (q&3)*4 .. +4
  const char* pbbase = (const char*)pb + (size_t)tg * 16 * 16384 + lane * 16;
#define BLOAD(buf, q)                                                         \
  {                                                                           \
    const char* p_ = pbbase + (size_t)((q) >> 2) * 16384 + ((q) & 3) * 4096;  \
    _Pragma("unroll") for (int k_ = 0; k_ < 4; ++k_)                          \
        buf[k_] = *(const s8v*)(p_ + k_ * 1024);                              \
  }
#define MFMA4(bb, kh)                                                         \
  __builtin_amdgcn_s_setprio(1);                                             \
  _Pragma("unroll") for (int k_ = 0; k_ < 4; ++k_) {                          \
    acc[0][k_ & 1] = __builtin_amdgcn_mfma_f32_16x16x32_bf16(                 \
        a[0][(kh) * 4 + k_], bb[k_], acc[0][k_ & 1], 0, 0, 0);                \
    acc[1][k_ & 1] = __builtin_amdgcn_mfma_f32_16x16x32_bf16(                 \
        a[1][(kh) * 4 + k_], bb[k_], acc[1][k_ & 1], 0, 0, 0);                \
  }                                                                           \
  __builtin_amdgcn_s_setprio(0);

  s8v br[4][4];  // 4-slot ring, 64 VGPR; depth-3 prefetch (12 loads in flight)
  BLOAD(br[0], 0);
  BLOAD(br[1], 1);
  BLOAD(br[2], 2);

#pragma unroll
  for (int i = 0; i < 16; ++i) {
    const int ct = tg * 16 + i;
    const int cls = ct * 16 + (lane & 15);
    const bool valid = cls < kC;

    f4v acc[2][2] = {{{0.f,0.f,0.f,0.f},{0.f,0.f,0.f,0.f}},
                     {{0.f,0.f,0.f,0.f},{0.f,0.f,0.f,0.f}}};
#pragma unroll
    for (int qq = 0; qq < 4; ++qq) {
      const int q = i * 4 + qq;
      if (q + 3 < 64) BLOAD(br[(q + 3) & 3], q + 3);  // refill slot freed last step
      MFMA4(br[q & 3], qq);
    }

    // lean fold: 1 exp + 1 add + label-capture per logit
#pragma unroll
    for (int rt = 0; rt < 2; ++rt) {
#pragma unroll
      for (int r = 0; r < 4; ++r) {
        const int s = rt * 4 + r;
        float lg = valid ? (acc[rt][0][r] + acc[rt][1][r]) : -1e30f;
        zl[s] = (cls == lab[s]) ? lg : zl[s];
        l[s] += __expf(lg);
      }
    }
  }
#undef BLOAD
#undef MFMA4

  __syncthreads();  // all waves done reading A -> safe to overlay Sf on Ab

  // merge 16 lanes of each quarter, publish (L, Z) per (row, tg)
#pragma unroll
  for (int s = 0; s < 8; ++s) {
    float L = l[s];
    L += __shfl_xor(L, 1, 64);
    L += __shfl_xor(L, 2, 64);
    L += __shfl_xor(L, 4, 64);
    L += __shfl_xor(L, 8, 64);
    float Z = zl[s];
    Z += __shfl_xor(Z, 1, 64);
    Z += __shfl_xor(Z, 2, 64);
    Z += __shfl_xor(Z, 4, 64);
    Z += __shfl_xor(Z, 8, 64);
    if ((lane & 15) == 0) {
      const int row = rg * 32 + (s >> 2) * 16 + ((lane >> 4) << 2) + (s & 3);
      Sf[(row * 4 + tg) * 2 + 0] = L;
      Sf[(row * 4 + tg) * 2 + 1] = Z;
    }
  }
  __syncthreads();

  // first 64 threads: one row each -> nll = log(sum_l) - z_label
  if (t < 64) {
    float L = 0.f, Z = 0.f;
#pragma unroll
    for (int j = 0; j < 4; ++j) {
      L += Sf[(t * 4 + j) * 2 + 0];
      Z += Sf[(t * 4 + j) * 2 + 1];
    }
    float nll = logf(L) - Z;
    nll += __shfl_xor(nll, 1, 64);
    nll += __shfl_xor(nll, 2, 64);
    nll += __shfl_xor(nll, 4, 64);
    nll += __shfl_xor(nll, 8, 64);
    nll += __shfl_xor(nll, 16, 64);
    nll += __shfl_xor(nll, 32, 64);
    if (t == 0) atomicAdd(out, nll * (1.0f / (float)kB));
  }
}

}  // namespace

extern "C" void kernel_launch(void* const* d_in, const int* in_sizes, int n_in,
                              void* d_out, int out_size, void* d_ws, size_t ws_size,
                              hipStream_t stream) {
  const float* features = (const float*)d_in[0];
  const int* labels     = (const int*)d_in[1];
  const float* center   = (const float*)d_in[2];
  float* out = (float*)d_out;

  unsigned short* pb = (unsigned short*)d_ws;  // 64 tiles * 16 KB = 1 MB

  k_prep<<<64, 256, 0, stream>>>(center, pb, out);
  k_main<<<kB / 64, 512, 0, stream>>>(features, labels, pb, out);
}

// Round 7
// 39.679 us; speedup vs baseline: 1.7448x; 1.7448x over previous
//
#include <hip/hip_runtime.h>
#include <math.h>

namespace {

constexpr int kB = 16384;  // batch rows
constexpr int kD = 512;    // feature dim
constexpr int kC = 1000;   // classes
constexpr float kScale = 64.f;          // center pre-scale (avoids e4m3 subnormals)
constexpr float kSinv  = 1.f / 64.f;

typedef __attribute__((ext_vector_type(4))) float f4v;  // MFMA acc
typedef long long i64b;                                  // fp8 MFMA operand (8 bytes)
union BU { uint4 v; i64b d[2]; };

// pack 4 f32 -> 4 fp8 e4m3 (OCP) bytes in a u32
__device__ inline unsigned int pk4(float a, float b, float c, float d) {
  int r = __builtin_amdgcn_cvt_pk_fp8_f32(a, b, 0, false);
  r = __builtin_amdgcn_cvt_pk_fp8_f32(c, d, r, true);
  return (unsigned int)r;
}

// --- k_prep: fused column-norm + pack normalized*64 fp8 B-fragments ------
// 65 blocks x 256 threads; block = one 16-col class tile (tiles 62.5+ zero).
// Layout: pb[tile][kspair 0..7][lane 0..63][16B]; 16B = frag ks=2p (lo 8B)
// and ks=2p+1 (hi 8B); frag elem j -> center[ks*32+(lane>>4)*8+j][tile*16+(lane&15)]
__global__ __launch_bounds__(256)
void k_prep(const float* __restrict__ center, unsigned char* __restrict__ pb,
            float* __restrict__ out) {
  if (blockIdx.x == 0 && threadIdx.x == 0) out[0] = 0.f;  // zero accumulator
  __shared__ float Ct[kD][16];  // 32 KB
  __shared__ float P[16][16];
  __shared__ float inv[16];
  const int t = threadIdx.x, ct = blockIdx.x;
  const int col = t & 15, dg = t >> 4;
  const int cc = ct * 16 + col;
  float s = 0.f;
#pragma unroll 8
  for (int j = 0; j < 32; ++j) {
    int d = dg * 32 + j;
    float v = (cc < kC) ? center[(size_t)d * kC + cc] : 0.f;
    Ct[d][col] = v;
    s = fmaf(v, v, s);
  }
  P[dg][col] = s;
  __syncthreads();
  if (t < 16) {
    float tot = 0.f;
#pragma unroll
    for (int j = 0; j < 16; ++j) tot += P[j][t];
    inv[t] = rsqrtf(fmaxf(tot, 1e-24f)) * kScale;
  }
  __syncthreads();
#pragma unroll
  for (int pi = 0; pi < 4; ++pi) {
    int p = t * 4 + pi;            // 1024 (ks,lane) fragment-slots
    int ks = p >> 6, lane = p & 63;
    int cl = lane & 15, d0 = ks * 32 + ((lane >> 4) << 3);
    float iv = inv[cl];
    unsigned int lo = pk4(Ct[d0 + 0][cl] * iv, Ct[d0 + 1][cl] * iv,
                          Ct[d0 + 2][cl] * iv, Ct[d0 + 3][cl] * iv);
    unsigned int hi = pk4(Ct[d0 + 4][cl] * iv, Ct[d0 + 5][cl] * iv,
                          Ct[d0 + 6][cl] * iv, Ct[d0 + 7][cl] * iv);
    *(uint2*)(pb + (size_t)ct * 8192 + (ks >> 1) * 1024 + lane * 16 + (ks & 1) * 8) =
        make_uint2(lo, hi);
  }
}

// --- k_main: fp8 pinned-A + 8-slot B-ring (6 loads in flight) + softmax ---
// 512 blocks x 256 threads (4 waves), target 3 blocks/CU. Block = 32 rows.
// Wave w owns class tiles w*16..+16. A (32 rows x 512 k fp8) in 64 pinned
// VGPRs; B streams from L2 via register ring, vmcnt never drained in loop.
__global__ __launch_bounds__(256, 3)
void k_main(const float* __restrict__ features,
            const int* __restrict__ labels,
            const unsigned char* __restrict__ pb,
            float* __restrict__ out) {
  __shared__ __align__(16) unsigned char Ab[32 * kD];  // 16 KB fp8, swizzled
  float* Sf = (float*)Ab;  // overlay for final merge (A dead by then)
  const int t = threadIdx.x;
  const int w = t >> 6, lane = t & 63;
  const int b0r = blockIdx.x * 32;

  // stage 32x512 f32 -> fp8 -> LDS; 8B chunks, XOR swizzle on 8B granule
#pragma unroll
  for (int i = 0; i < 8; ++i) {
    int ci = i * 256 + t;
    int row = ci >> 6, kc = ci & 63;
    const float* src = features + (size_t)(b0r + row) * kD + kc * 8;
    float4 f0 = *(const float4*)src;
    float4 f1 = *(const float4*)(src + 4);
    unsigned int lo = pk4(f0.x, f0.y, f0.z, f0.w);
    unsigned int hi = pk4(f1.x, f1.y, f1.z, f1.w);
    *(uint2*)(Ab + row * 512 + ((kc * 8) ^ ((row & 7) << 3))) = make_uint2(lo, hi);
  }
  __syncthreads();

  // load this wave's 32 rows x K=512 of A into 64 VGPRs, then PIN them
  i64b a8[2][16];
#pragma unroll
  for (int rt = 0; rt < 2; ++rt) {
    const int row = rt * 16 + (lane & 15);
    const int rb = row * 512, swz = (row & 7) << 3;
#pragma unroll
    for (int ks = 0; ks < 16; ++ks) {
      const int kc = ks * 4 + (lane >> 4);
      a8[rt][ks] = *(const i64b*)(Ab + rb + ((kc * 8) ^ swz));
    }
  }
#pragma unroll
  for (int rt = 0; rt < 2; ++rt)
#pragma unroll
    for (int ks = 0; ks < 16; ++ks)
      asm volatile("" : "+v"(a8[rt][ks]));

  // per-lane state (no running max: true logits ~N(0,1), exp is safe)
  float l[8], zl[8];
  int lab[8];
#pragma unroll
  for (int s = 0; s < 8; ++s) {
    l[s] = 0.f; zl[s] = 0.f;
    lab[s] = labels[b0r + (s >> 2) * 16 + ((lane >> 4) << 2) + (s & 3)];
  }

  // B ring: step = i*8+p -> slot p; prefetch distance 6 (6 loads in flight).
  // Max prefetched tile = w*16+16 <= 64 -> covered by the padded 65th tile.
  const unsigned char* pbw = pb + (size_t)(w * 16) * 8192 + lane * 16;
  uint4 br[8];
#pragma unroll
  for (int p = 0; p < 6; ++p) br[p] = *(const uint4*)(pbw + p * 1024);

#pragma unroll 1
  for (int i = 0; i < 16; ++i) {
    const unsigned char* pcur = pbw + (size_t)i * 8192;
    const int ct = w * 16 + i;
    const int cls = ct * 16 + (lane & 15);
    const bool valid = cls < kC;

    f4v acc[2][2] = {{{0.f,0.f,0.f,0.f},{0.f,0.f,0.f,0.f}},
                     {{0.f,0.f,0.f,0.f},{0.f,0.f,0.f,0.f}}};
#pragma unroll
    for (int p = 0; p < 8; ++p) {
      {  // prefetch step i*8+p+6 into slot (p+6)&7 (never collides with br[p])
        const int pp = p + 6;
        br[pp & 7] = *(const uint4*)(pcur + (pp >> 3) * 8192 + (pp & 7) * 1024);
      }
      BU b; b.v = br[p];
      __builtin_amdgcn_s_setprio(1);
      acc[0][0] = __builtin_amdgcn_mfma_f32_16x16x32_fp8_fp8(a8[0][2*p],   b.d[0], acc[0][0], 0, 0, 0);
      acc[1][0] = __builtin_amdgcn_mfma_f32_16x16x32_fp8_fp8(a8[1][2*p],   b.d[0], acc[1][0], 0, 0, 0);
      acc[0][1] = __builtin_amdgcn_mfma_f32_16x16x32_fp8_fp8(a8[0][2*p+1], b.d[1], acc[0][1], 0, 0, 0);
      acc[1][1] = __builtin_amdgcn_mfma_f32_16x16x32_fp8_fp8(a8[1][2*p+1], b.d[1], acc[1][1], 0, 0, 0);
      __builtin_amdgcn_s_setprio(0);
    }

    // lean fold on raw (x64-scaled) logits: 1 mul+exp+add + capture each
#pragma unroll
    for (int rt = 0; rt < 2; ++rt) {
#pragma unroll
      for (int r = 0; r < 4; ++r) {
        const int s = rt * 4 + r;
        float lg = valid ? (acc[rt][0][r] + acc[rt][1][r]) : -1e30f;
        zl[s] = (cls == lab[s]) ? lg : zl[s];
        l[s] += __expf(lg * kSinv);
      }
    }
  }

  __syncthreads();  // all waves past A reads -> safe to overlay Sf on Ab

  // merge 16 lanes of each quarter, publish (L, Zraw) per (row, wave)
#pragma unroll
  for (int s = 0; s < 8; ++s) {
    float L = l[s];
    L += __shfl_xor(L, 1, 64);
    L += __shfl_xor(L, 2, 64);
    L += __shfl_xor(L, 4, 64);
    L += __shfl_xor(L, 8, 64);
    float Z = zl[s];
    Z += __shfl_xor(Z, 1, 64);
    Z += __shfl_xor(Z, 2, 64);
    Z += __shfl_xor(Z, 4, 64);
    Z += __shfl_xor(Z, 8, 64);
    if ((lane & 15) == 0) {
      const int row = (s >> 2) * 16 + ((lane >> 4) << 2) + (s & 3);
      Sf[(row * 4 + w) * 2 + 0] = L;
      Sf[(row * 4 + w) * 2 + 1] = Z;
    }
  }
  __syncthreads();

  // wave 0: one row per thread -> nll = log(sum_l) - z_label/64
  if (t < 64) {
    float nll = 0.f;
    if (t < 32) {
      float L = 0.f, Z = 0.f;
#pragma unroll
      for (int j = 0; j < 4; ++j) {
        L += Sf[(t * 4 + j) * 2 + 0];
        Z += Sf[(t * 4 + j) * 2 + 1];
      }
      nll = logf(L) - Z * kSinv;
    }
    nll += __shfl_xor(nll, 1, 64);
    nll += __shfl_xor(nll, 2, 64);
    nll += __shfl_xor(nll, 4, 64);
    nll += __shfl_xor(nll, 8, 64);
    nll += __shfl_xor(nll, 16, 64);
    nll += __shfl_xor(nll, 32, 64);
    if (t == 0) atomicAdd(out, nll * (1.0f / (float)kB));
  }
}

}  // namespace

extern "C" void kernel_launch(void* const* d_in, const int* in_sizes, int n_in,
                              void* d_out, int out_size, void* d_ws, size_t ws_size,
                              hipStream_t stream) {
  const float* features = (const float*)d_in[0];
  const int* labels     = (const int*)d_in[1];
  const float* center   = (const float*)d_in[2];
  float* out = (float*)d_out;

  unsigned char* pb = (unsigned char*)d_ws;  // 65 tiles * 8 KB = 520 KB

  k_prep<<<65, 256, 0, stream>>>(center, pb, out);
  k_main<<<kB / 32, 256, 0, stream>>>(features, labels, pb, out);
}